// Round 1
// baseline (81.443 us; speedup 1.0000x reference)
//
#include <hip/hip_runtime.h>
#include <hip/hip_bf16.h>
#include <math.h>

#define BB 16
#define TT 128
#define MM 32
#define PP 64
#define CC 256

// ---------------- k1: w_in -> eff_c, eff_p  (one block per (b,m)) ----------
__global__ void k1_gather(const float* __restrict__ pointers,
                          const float* __restrict__ contents,
                          const float* __restrict__ receivers,
                          float* __restrict__ eff_c,
                          float* __restrict__ eff_p) {
    const int bm = blockIdx.x;
    const int b = bm >> 5, m = bm & 31;
    const int tid = threadIdx.x;
    __shared__ float w_in[TT];
    if (tid < TT) {
        float s = 0.f;
        const float* pr = pointers + (b * TT + tid) * PP;
        const float* rc = receivers + m * PP;
        #pragma unroll 8
        for (int p = 0; p < PP; ++p) s += rc[p] * pr[p];
        float th = tanhf(s);
        w_in[tid] = th > 0.f ? th : 0.f;
    }
    __syncthreads();
    // eff_c[c] = sum_t w_in[t] * contents[b,t,c]   (tid = c, coalesced)
    {
        float acc = 0.f;
        const float* cb = contents + b * TT * CC + tid;
        #pragma unroll 4
        for (int t = 0; t < TT; ++t) acc += w_in[t] * cb[t * CC];
        eff_c[bm * CC + tid] = acc;
    }
    // eff_p[p] = sum_t w_in[t] * pointers[b,t,p]
    if (tid < PP) {
        float acc = 0.f;
        const float* pb = pointers + b * TT * PP + tid;
        #pragma unroll 4
        for (int t = 0; t < TT; ++t) acc += w_in[t] * pb[t * PP];
        eff_p[bm * PP + tid] = acc;
    }
}

// ------------- k2: out_c = mem[m] @ eff_c ; routing MLP -> out_p -----------
__global__ void k2_mem_mlp(const float* __restrict__ memories,
                           const float* __restrict__ W1,
                           const float* __restrict__ b1,
                           const float* __restrict__ W2,
                           const float* __restrict__ b2,
                           const float* __restrict__ eff_c,
                           const float* __restrict__ eff_p,
                           float* __restrict__ outp_g,
                           float* __restrict__ outc_g) {
    const int bm = blockIdx.x;
    const int m = bm & 31;
    const int tid = threadIdx.x;
    const int wave = tid >> 6, lane = tid & 63;
    __shared__ float ec[CC];
    __shared__ float ri[PP + CC];   // routing_in = [eff_p | eff_c]
    __shared__ float outc_s[CC];
    __shared__ float part[4][PP];
    __shared__ float h[PP];

    {
        float ecv = eff_c[bm * CC + tid];
        ec[tid] = ecv;
        ri[PP + tid] = ecv;
    }
    if (tid < PP) ri[tid] = eff_p[bm * PP + tid];
    __syncthreads();

    // out_c: wave w handles rows c = w*64 .. w*64+63; 64 lanes x float4 = row
    {
        const float4* mem4 = reinterpret_cast<const float4*>(memories + m * CC * CC);
        const float e0 = ec[lane * 4 + 0], e1 = ec[lane * 4 + 1];
        const float e2 = ec[lane * 4 + 2], e3 = ec[lane * 4 + 3];
        for (int r = 0; r < 64; ++r) {
            const int c = wave * 64 + r;
            float4 mv = mem4[c * 64 + lane];
            float pp = mv.x * e0 + mv.y * e1 + mv.z * e2 + mv.w * e3;
            #pragma unroll
            for (int off = 32; off; off >>= 1) pp += __shfl_xor(pp, off, 64);
            if (lane == 0) outc_s[c] = pp;
        }
    }
    __syncthreads();
    outc_g[bm * CC + tid] = outc_s[tid];

    // h = relu(routing_in @ W1 + b1): o = tid&63, 4 segments of 80 over i
    {
        const int o = tid & 63, seg = tid >> 6;
        const float* w1 = W1 + m * 320 * 64;
        float acc = 0.f;
        const int i0 = seg * 80;
        #pragma unroll 8
        for (int i = i0; i < i0 + 80; ++i) acc += ri[i] * w1[i * 64 + o];
        part[seg][o] = acc;
    }
    __syncthreads();
    if (tid < PP) {
        float s = part[0][tid] + part[1][tid] + part[2][tid] + part[3][tid] + b1[m * PP + tid];
        h[tid] = s > 0.f ? s : 0.f;
    }
    __syncthreads();
    // out_p = relu(h @ W2 + b2)
    {
        const int o = tid & 63, seg = tid >> 6;
        const float* w2 = W2 + m * 64 * 64;
        float acc = 0.f;
        const int i0 = seg * 16;
        #pragma unroll
        for (int i = i0; i < i0 + 16; ++i) acc += h[i] * w2[i * 64 + o];
        part[seg][o] = acc;
    }
    __syncthreads();
    if (tid < PP) {
        float s = part[0][tid] + part[1][tid] + part[2][tid] + part[3][tid] + b2[m * PP + tid];
        outp_g[bm * PP + tid] = s > 0.f ? s : 0.f;
    }
}

// ------- k3: w_out, eff_out_c, normed_in  (one block per (b,m)) ------------
__global__ void k3_route(const float* __restrict__ outp_g,
                         const float* __restrict__ outc_g,
                         const float* __restrict__ eff_c,
                         float* __restrict__ eoc_g,
                         float* __restrict__ nrm_g) {
    const int bm = blockIdx.x;
    const int b = bm >> 5;
    const int tid = threadIdx.x;
    __shared__ float op[PP];
    __shared__ float wout[MM];
    __shared__ float red[4];
    if (tid < PP) op[tid] = outp_g[bm * PP + tid];
    __syncthreads();
    if (tid < MM) {
        float acc = 0.f;
        const float* opn = outp_g + (b * MM + tid) * PP;
        #pragma unroll 8
        for (int p = 0; p < PP; ++p) acc += op[p] * opn[p];
        float th = tanhf(acc);
        wout[tid] = th > 0.f ? th : 0.f;
    }
    __syncthreads();
    // eff_out_c[c] = sum_n wout[n] * out_c[b,n,c]
    {
        float acc = 0.f;
        const float* cb = outc_g + b * MM * CC + tid;
        #pragma unroll
        for (int n = 0; n < MM; ++n) acc += wout[n] * cb[n * CC];
        eoc_g[bm * CC + tid] = acc;
    }
    // normed_in = eff_c / (||eff_c||^2 + eps)
    {
        float ecv = eff_c[bm * CC + tid];
        float v = ecv * ecv;
        #pragma unroll
        for (int off = 32; off; off >>= 1) v += __shfl_xor(v, off, 64);
        const int wave = tid >> 6, lane = tid & 63;
        if (lane == 0) red[wave] = v;
        __syncthreads();
        float ss = red[0] + red[1] + red[2] + red[3];
        nrm_g[bm * CC + tid] = ecv / (ss + 1e-42f);
    }
}

// ---------- k4: mems_out = 0.5*(memories[m] + eoc[c]*nrm[d]) ---------------
__global__ void k4_update(const float* __restrict__ memories,
                          const float* __restrict__ eoc_g,
                          const float* __restrict__ nrm_g,
                          float* __restrict__ mems_out) {
    const int i = blockIdx.x * 256 + threadIdx.x;   // float4 index, < 8388608
    const int d4 = i & 63;
    const int c  = (i >> 6) & 255;
    const int bm = i >> 14;
    const int m  = bm & 31;
    const float4* mem4 = reinterpret_cast<const float4*>(memories);
    const float4* nrm4 = reinterpret_cast<const float4*>(nrm_g);
    float4 mv = mem4[((m * CC + c) << 6) + d4];
    float4 nv = nrm4[(bm << 6) + d4];
    const float e = eoc_g[bm * CC + c];
    float4 o;
    o.x = 0.5f * (mv.x + e * nv.x);
    o.y = 0.5f * (mv.y + e * nv.y);
    o.z = 0.5f * (mv.z + e * nv.z);
    o.w = 0.5f * (mv.w + e * nv.w);
    reinterpret_cast<float4*>(mems_out)[i] = o;
}

extern "C" void kernel_launch(void* const* d_in, const int* in_sizes, int n_in,
                              void* d_out, int out_size, void* d_ws, size_t ws_size,
                              hipStream_t stream) {
    const float* pointers  = (const float*)d_in[0];
    const float* contents  = (const float*)d_in[1];
    const float* receivers = (const float*)d_in[2];
    const float* memories  = (const float*)d_in[3];
    const float* W1 = (const float*)d_in[4];
    const float* b1 = (const float*)d_in[5];
    const float* W2 = (const float*)d_in[6];
    const float* b2 = (const float*)d_in[7];

    float* out      = (float*)d_out;
    float* outp_g   = out;                       // 16*32*64   = 32768
    float* outc_g   = out + 32768;               // 16*32*256  = 131072
    float* mems_out = out + 32768 + 131072;      // 16*32*256*256

    float* ws    = (float*)d_ws;
    float* eff_c = ws;                 // 131072
    float* eff_p = ws + 131072;        // 32768
    float* eoc   = ws + 163840;        // 131072
    float* nrm   = ws + 294912;        // 131072  (total 425984 f32 = 1.7 MB)

    hipLaunchKernelGGL(k1_gather, dim3(BB * MM), dim3(256), 0, stream,
                       pointers, contents, receivers, eff_c, eff_p);
    hipLaunchKernelGGL(k2_mem_mlp, dim3(BB * MM), dim3(256), 0, stream,
                       memories, W1, b1, W2, b2, eff_c, eff_p, outp_g, outc_g);
    hipLaunchKernelGGL(k3_route, dim3(BB * MM), dim3(256), 0, stream,
                       outp_g, outc_g, eff_c, eoc, nrm);
    hipLaunchKernelGGL(k4_update, dim3((BB * MM * CC * CC / 4) / 256), dim3(256), 0, stream,
                       memories, eoc, nrm, mems_out);
}

// Round 2
// 74.860 us; speedup vs baseline: 1.0879x; 1.0879x over previous
//
#include <hip/hip_runtime.h>
#include <math.h>

#define BB 16
#define TT 128
#define MM 32
#define PP 64
#define CC 256

// ---- kA: w_in -> eff_c (ws), eff_p (LDS), routing MLP -> out_p ------------
// one block per (b,m), 256 threads
__global__ void kA_front(const float* __restrict__ pointers,
                         const float* __restrict__ contents,
                         const float* __restrict__ receivers,
                         const float* __restrict__ W1,
                         const float* __restrict__ b1,
                         const float* __restrict__ W2,
                         const float* __restrict__ b2,
                         float* __restrict__ eff_c_ws,
                         float* __restrict__ outp_g) {
    const int bm = blockIdx.x;
    const int b = bm >> 5, m = bm & 31;
    const int tid = threadIdx.x;
    __shared__ float w_in[TT];
    __shared__ float ri[PP + CC];   // [eff_p | eff_c]
    __shared__ float part[4][PP];
    __shared__ float h[PP];

    if (tid < TT) {
        float s = 0.f;
        const float* pr = pointers + (b * TT + tid) * PP;
        const float* rc = receivers + m * PP;
        #pragma unroll 8
        for (int p = 0; p < PP; ++p) s += rc[p] * pr[p];
        float th = tanhf(s);
        w_in[tid] = th > 0.f ? th : 0.f;
    }
    __syncthreads();
    {   // eff_c[c], c = tid (coalesced over c)
        float acc = 0.f;
        const float* cb = contents + b * TT * CC + tid;
        #pragma unroll 4
        for (int t = 0; t < TT; ++t) acc += w_in[t] * cb[t * CC];
        ri[PP + tid] = acc;
        eff_c_ws[bm * CC + tid] = acc;
    }
    if (tid < PP) {   // eff_p[p]
        float acc = 0.f;
        const float* pb = pointers + b * TT * PP + tid;
        #pragma unroll 4
        for (int t = 0; t < TT; ++t) acc += w_in[t] * pb[t * PP];
        ri[tid] = acc;
    }
    __syncthreads();
    // h = relu(ri @ W1 + b1): o = tid&63, 4 segments of 80 over i
    {
        const int o = tid & 63, seg = tid >> 6;
        const float* w1 = W1 + m * 320 * 64;
        float acc = 0.f;
        const int i0 = seg * 80;
        #pragma unroll 8
        for (int i = i0; i < i0 + 80; ++i) acc += ri[i] * w1[i * 64 + o];
        part[seg][o] = acc;
    }
    __syncthreads();
    if (tid < PP) {
        float s = part[0][tid] + part[1][tid] + part[2][tid] + part[3][tid] + b1[m * PP + tid];
        h[tid] = s > 0.f ? s : 0.f;
    }
    __syncthreads();
    {
        const int o = tid & 63, seg = tid >> 6;
        const float* w2 = W2 + m * 64 * 64;
        float acc = 0.f;
        const int i0 = seg * 16;
        #pragma unroll
        for (int i = i0; i < i0 + 16; ++i) acc += h[i] * w2[i * 64 + o];
        part[seg][o] = acc;
    }
    __syncthreads();
    if (tid < PP) {
        float s = part[0][tid] + part[1][tid] + part[2][tid] + part[3][tid] + b2[m * PP + tid];
        outp_g[bm * PP + tid] = s > 0.f ? s : 0.f;
    }
}

// ---- kC: out_c = mem[m] @ eff_c, 4 batches per block ----------------------
// grid = 32 modules * 4 batch-quads, 512 threads (8 waves, 32 rows each)
__global__ void kC_outc(const float* __restrict__ memories,
                        const float* __restrict__ eff_c_ws,
                        float* __restrict__ outc_g) {
    const int m = blockIdx.x >> 2, bq = blockIdx.x & 3;
    const int tid = threadIdx.x;
    const int w = tid >> 6, lane = tid & 63;
    __shared__ float outc_s[4][CC];
    float4 e[4];
    #pragma unroll
    for (int j = 0; j < 4; ++j) {
        const int b = bq * 4 + j;
        e[j] = *reinterpret_cast<const float4*>(eff_c_ws + (b * MM + m) * CC + lane * 4);
    }
    const float4* mem4 = reinterpret_cast<const float4*>(memories) + m * (CC * CC / 4);
    for (int r = 0; r < 32; ++r) {
        const int c = w * 32 + r;
        float4 mv = mem4[c * 64 + lane];
        float p0 = mv.x * e[0].x + mv.y * e[0].y + mv.z * e[0].z + mv.w * e[0].w;
        float p1 = mv.x * e[1].x + mv.y * e[1].y + mv.z * e[1].z + mv.w * e[1].w;
        float p2 = mv.x * e[2].x + mv.y * e[2].y + mv.z * e[2].z + mv.w * e[2].w;
        float p3 = mv.x * e[3].x + mv.y * e[3].y + mv.z * e[3].z + mv.w * e[3].w;
        #pragma unroll
        for (int off = 32; off; off >>= 1) {
            p0 += __shfl_xor(p0, off, 64);
            p1 += __shfl_xor(p1, off, 64);
            p2 += __shfl_xor(p2, off, 64);
            p3 += __shfl_xor(p3, off, 64);
        }
        if (lane == 0) {
            outc_s[0][c] = p0; outc_s[1][c] = p1; outc_s[2][c] = p2; outc_s[3][c] = p3;
        }
    }
    __syncthreads();
    for (int idx = tid; idx < 4 * CC; idx += 512) {
        const int j = idx >> 8, c = idx & 255;
        outc_g[((bq * 4 + j) * MM + m) * CC + c] = outc_s[j][c];
    }
}

// ---- kB: w_out, eoc, nrm in LDS; stream 0.5*(mem + eoc*nrm^T) -------------
// one block per (b,m), 1024 threads
__global__ void kB_update(const float* __restrict__ memories,
                          const float* __restrict__ eff_c_ws,
                          const float* __restrict__ outp_g,
                          const float* __restrict__ outc_g,
                          float* __restrict__ mems_out) {
    const int bm = blockIdx.x;
    const int b = bm >> 5, m = bm & 31;
    const int tid = threadIdx.x;
    __shared__ float op_s[PP];
    __shared__ float wout[MM];
    __shared__ float part[4][CC];
    __shared__ float eoc_s[CC];
    __shared__ float4 nrm4_s[PP];     // 256 floats, float4-view
    __shared__ float red[4];

    if (tid < PP) op_s[tid] = outp_g[bm * PP + tid];
    __syncthreads();
    // w_out[n] = relu(tanh(out_p[b,m,:] . out_p[b,n,:])), 32 lanes per n
    {
        const int n = tid >> 5, j = tid & 31;
        const float* opn = outp_g + (b * MM + n) * PP;
        float v = op_s[2 * j] * opn[2 * j] + op_s[2 * j + 1] * opn[2 * j + 1];
        #pragma unroll
        for (int off = 16; off; off >>= 1) v += __shfl_xor(v, off, 32);
        if (j == 0) {
            float th = tanhf(v);
            wout[n] = th > 0.f ? th : 0.f;
        }
    }
    __syncthreads();
    // eoc[c] = sum_n wout[n] * out_c[b,n,c]; 4 n-groups of 8
    {
        const int c = tid & 255, nq = tid >> 8;
        const float* cb = outc_g + b * MM * CC + c;
        float acc = 0.f;
        #pragma unroll
        for (int k = 0; k < 8; ++k) acc += wout[nq * 8 + k] * cb[(nq * 8 + k) * CC];
        part[nq][c] = acc;
    }
    __syncthreads();
    if (tid < CC) {
        eoc_s[tid] = part[0][tid] + part[1][tid] + part[2][tid] + part[3][tid];
        float ec = eff_c_ws[bm * CC + tid];
        float v = ec * ec;
        #pragma unroll
        for (int off = 32; off; off >>= 1) v += __shfl_xor(v, off, 64);
        if ((tid & 63) == 0) red[tid >> 6] = v;
        reinterpret_cast<float*>(nrm4_s)[tid] = ec;
    }
    __syncthreads();
    if (tid < CC) {
        const float ss = red[0] + red[1] + red[2] + red[3];
        reinterpret_cast<float*>(nrm4_s)[tid] =
            reinterpret_cast<float*>(nrm4_s)[tid] / (ss + 1e-42f);
    }
    __syncthreads();
    // stream the 256x256 tile: 16384 float4, 16 per thread, fully coalesced
    const float4* mem4 = reinterpret_cast<const float4*>(memories) + m * (CC * CC / 4);
    float4* out4 = reinterpret_cast<float4*>(mems_out) + bm * (CC * CC / 4);
    for (int i = tid; i < CC * CC / 4; i += 1024) {
        const int c = i >> 6, d4 = i & 63;
        float4 mv = mem4[i];
        float4 nv = nrm4_s[d4];
        const float e = eoc_s[c];
        float4 o;
        o.x = 0.5f * (mv.x + e * nv.x);
        o.y = 0.5f * (mv.y + e * nv.y);
        o.z = 0.5f * (mv.z + e * nv.z);
        o.w = 0.5f * (mv.w + e * nv.w);
        out4[i] = o;
    }
}

extern "C" void kernel_launch(void* const* d_in, const int* in_sizes, int n_in,
                              void* d_out, int out_size, void* d_ws, size_t ws_size,
                              hipStream_t stream) {
    const float* pointers  = (const float*)d_in[0];
    const float* contents  = (const float*)d_in[1];
    const float* receivers = (const float*)d_in[2];
    const float* memories  = (const float*)d_in[3];
    const float* W1 = (const float*)d_in[4];
    const float* b1 = (const float*)d_in[5];
    const float* W2 = (const float*)d_in[6];
    const float* b2 = (const float*)d_in[7];

    float* out      = (float*)d_out;
    float* outp_g   = out;                       // 16*32*64
    float* outc_g   = out + 32768;               // 16*32*256
    float* mems_out = out + 32768 + 131072;      // 16*32*256*256

    float* eff_c = (float*)d_ws;                 // 131072 floats

    hipLaunchKernelGGL(kA_front, dim3(BB * MM), dim3(256), 0, stream,
                       pointers, contents, receivers, W1, b1, W2, b2, eff_c, outp_g);
    hipLaunchKernelGGL(kC_outc, dim3(MM * 4), dim3(512), 0, stream,
                       memories, eff_c, outc_g);
    hipLaunchKernelGGL(kB_update, dim3(BB * MM), dim3(1024), 0, stream,
                       memories, eff_c, outp_g, outc_g, mems_out);
}

// Round 3
// 65.823 us; speedup vs baseline: 1.2373x; 1.1373x over previous
//
#include <hip/hip_runtime.h>
#include <math.h>

#define BB 16
#define TT 128
#define MM 32
#define PP 64
#define CC 256

// ---- K1: per (b,m): w_in -> eff_c, eff_p; out_c = mem[m]@eff_c; MLP -> out_p
// 512 threads (8 waves)
__global__ __launch_bounds__(512) void K1_front(
        const float* __restrict__ pointers,
        const float* __restrict__ contents,
        const float* __restrict__ receivers,
        const float* __restrict__ memories,
        const float* __restrict__ W1,
        const float* __restrict__ b1,
        const float* __restrict__ W2,
        const float* __restrict__ b2,
        float* __restrict__ eff_c_ws,
        float* __restrict__ outp_g,
        float* __restrict__ outc_g) {
    const int bm = blockIdx.x;
    const int b = bm >> 5, m = bm & 31;
    const int tid = threadIdx.x;
    const int lane = tid & 63, w = tid >> 6;

    __shared__ float w_in[TT];
    __shared__ float ri[PP + CC];      // [eff_p | eff_c]
    __shared__ float partc[2][CC];
    __shared__ float part8[8][PP];
    __shared__ float h[PP];
    __shared__ float outc_s[CC];

    // ---- w_in: 4 lanes per token, contiguous float4 reads ----
    {
        const int t = tid >> 2, q = tid & 3;
        const float4* pr4 = reinterpret_cast<const float4*>(pointers + (b * TT + t) * PP + q * 16);
        const float4* rc4 = reinterpret_cast<const float4*>(receivers + m * PP + q * 16);
        float s = 0.f;
        #pragma unroll
        for (int k = 0; k < 4; ++k) {
            float4 v = pr4[k], rv = rc4[k];
            s += v.x * rv.x + v.y * rv.y + v.z * rv.z + v.w * rv.w;
        }
        s += __shfl_xor(s, 1, 64);
        s += __shfl_xor(s, 2, 64);
        if (q == 0) {
            float th = tanhf(s);
            w_in[t] = th > 0.f ? th : 0.f;
        }
    }
    __syncthreads();
    // ---- eff_c partials: c = tid&255, 2 t-groups of 64 ----
    {
        const int c = tid & 255, g = tid >> 8;
        const float* cb = contents + (b * TT + g * 64) * CC + c;
        float acc = 0.f;
        #pragma unroll 4
        for (int t = 0; t < 64; ++t) acc += w_in[g * 64 + t] * cb[t * CC];
        partc[g][c] = acc;
    }
    // ---- eff_p partials: p = tid&63, 8 t-groups of 16 ----
    {
        const int p = tid & 63, g = tid >> 6;
        const float* pb = pointers + (b * TT + g * 16) * PP + p;
        float acc = 0.f;
        #pragma unroll
        for (int t = 0; t < 16; ++t) acc += w_in[g * 16 + t] * pb[t * PP];
        part8[g][p] = acc;
    }
    __syncthreads();
    if (tid < CC) {
        float e = partc[0][tid] + partc[1][tid];
        ri[PP + tid] = e;
        eff_c_ws[bm * CC + tid] = e;
    } else if (tid < CC + PP) {
        const int p = tid - CC;
        float a = 0.f;
        #pragma unroll
        for (int g = 0; g < 8; ++g) a += part8[g][p];
        ri[p] = a;
    }
    __syncthreads();

    // ---- out_c = mem[m] @ eff_c: wave w rows w*32..w*32+31, float4 + shfl ----
    {
        const float e0 = ri[PP + lane * 4 + 0], e1 = ri[PP + lane * 4 + 1];
        const float e2 = ri[PP + lane * 4 + 2], e3 = ri[PP + lane * 4 + 3];
        const float4* mem4 = reinterpret_cast<const float4*>(memories) + m * (CC * CC / 4);
        for (int r = 0; r < 32; ++r) {
            const int c = w * 32 + r;
            float4 mv = mem4[c * 64 + lane];
            float pp = mv.x * e0 + mv.y * e1 + mv.z * e2 + mv.w * e3;
            #pragma unroll
            for (int off = 32; off; off >>= 1) pp += __shfl_xor(pp, off, 64);
            if (lane == 0) outc_s[c] = pp;
        }
    }

    // ---- MLP: h = relu(ri @ W1 + b1) ----
    {
        const float* w1 = W1 + m * 320 * 64;
        float acc = 0.f;
        const int i0 = w * 40;
        #pragma unroll 8
        for (int i = i0; i < i0 + 40; ++i) acc += ri[i] * w1[i * 64 + lane];
        __syncthreads();               // also covers outc_s completion
        part8[w][lane] = acc;
    }
    __syncthreads();
    if (tid < PP) {
        float s = b1[m * PP + tid];
        #pragma unroll
        for (int g = 0; g < 8; ++g) s += part8[g][tid];
        h[tid] = s > 0.f ? s : 0.f;
    }
    if (tid >= CC && tid < CC + CC) { } // no-op spacing
    __syncthreads();
    {
        const float* w2 = W2 + m * 64 * 64;
        float acc = 0.f;
        const int i0 = w * 8;
        #pragma unroll
        for (int i = i0; i < i0 + 8; ++i) acc += h[i] * w2[i * 64 + lane];
        part8[w][lane] = acc;
    }
    __syncthreads();
    if (tid < PP) {
        float s = b2[m * PP + tid];
        #pragma unroll
        for (int g = 0; g < 8; ++g) s += part8[g][tid];
        outp_g[bm * PP + tid] = s > 0.f ? s : 0.f;
    }
    if (tid < CC) outc_g[bm * CC + tid] = outc_s[tid];
}

// ---- K2: per (b,m): w_out, eoc, nrm -> ws (256 threads) -------------------
__global__ __launch_bounds__(256) void K2_route(
        const float* __restrict__ outp_g,
        const float* __restrict__ outc_g,
        const float* __restrict__ eff_c_ws,
        float* __restrict__ eoc_ws,
        float* __restrict__ nrm_ws) {
    const int bm = blockIdx.x;
    const int b = bm >> 5;
    const int tid = threadIdx.x;
    __shared__ float op[PP];
    __shared__ float wout[MM];
    __shared__ float red[4];
    if (tid < PP) op[tid] = outp_g[bm * PP + tid];
    __syncthreads();
    // w_out[n]: 8 lanes per n
    {
        const int n = tid >> 3, j = tid & 7;
        const float* opn = outp_g + (b * MM + n) * PP + j * 8;
        float s = 0.f;
        #pragma unroll
        for (int k = 0; k < 8; ++k) s += op[j * 8 + k] * opn[k];
        s += __shfl_xor(s, 1, 64);
        s += __shfl_xor(s, 2, 64);
        s += __shfl_xor(s, 4, 64);
        if (j == 0) {
            float th = tanhf(s);
            wout[n] = th > 0.f ? th : 0.f;
        }
    }
    __syncthreads();
    // eoc[c] = sum_n wout[n]*out_c[b,n,c]
    {
        float acc = 0.f;
        const float* cb = outc_g + b * MM * CC + tid;
        #pragma unroll 4
        for (int n = 0; n < MM; ++n) acc += wout[n] * cb[n * CC];
        eoc_ws[bm * CC + tid] = acc;
    }
    // nrm = eff_c / (||eff_c||^2 + eps)
    {
        float ec = eff_c_ws[bm * CC + tid];
        float v = ec * ec;
        #pragma unroll
        for (int off = 32; off; off >>= 1) v += __shfl_xor(v, off, 64);
        if ((tid & 63) == 0) red[tid >> 6] = v;
        __syncthreads();
        const float ss = red[0] + red[1] + red[2] + red[3];
        nrm_ws[bm * CC + tid] = ec / (ss + 1e-42f);
    }
}

// ---- K3: pure stream: out = 0.5*(mem + eoc (x) nrm) -----------------------
// grid = 8192: gid = (m*16 + cq)*16 + b; block covers 16 c-rows, contiguous 16 KB
__global__ __launch_bounds__(256) void K3_stream(
        const float* __restrict__ memories,
        const float* __restrict__ eoc_ws,
        const float* __restrict__ nrm_ws,
        float* __restrict__ mems_out) {
    const int gid = blockIdx.x;
    const int b = gid & 15;
    const int mcq = gid >> 4;
    const int m = mcq >> 4, cq = mcq & 15;
    const int bm = b * MM + m;
    const int tid = threadIdx.x;
    const int lane = tid & 63, w = tid >> 6;

    const float4 nv = reinterpret_cast<const float4*>(nrm_ws)[bm * 64 + lane];
    const float4* mem4 = reinterpret_cast<const float4*>(memories) + m * (CC * CC / 4) + cq * 1024;
    float4* out4 = reinterpret_cast<float4*>(mems_out) + bm * (CC * CC / 4) + cq * 1024;
    const float* eoc = eoc_ws + bm * CC + cq * 16;

    #pragma unroll
    for (int k = 0; k < 4; ++k) {
        const int idx = k * 256 + tid;
        const float e = eoc[k * 4 + w];
        float4 mv = mem4[idx];
        float4 o;
        o.x = 0.5f * (mv.x + e * nv.x);
        o.y = 0.5f * (mv.y + e * nv.y);
        o.z = 0.5f * (mv.z + e * nv.z);
        o.w = 0.5f * (mv.w + e * nv.w);
        out4[idx] = o;
    }
}

extern "C" void kernel_launch(void* const* d_in, const int* in_sizes, int n_in,
                              void* d_out, int out_size, void* d_ws, size_t ws_size,
                              hipStream_t stream) {
    const float* pointers  = (const float*)d_in[0];
    const float* contents  = (const float*)d_in[1];
    const float* receivers = (const float*)d_in[2];
    const float* memories  = (const float*)d_in[3];
    const float* W1 = (const float*)d_in[4];
    const float* b1 = (const float*)d_in[5];
    const float* W2 = (const float*)d_in[6];
    const float* b2 = (const float*)d_in[7];

    float* out      = (float*)d_out;
    float* outp_g   = out;                       // 16*32*64
    float* outc_g   = out + 32768;               // 16*32*256
    float* mems_out = out + 32768 + 131072;      // 16*32*256*256

    float* ws    = (float*)d_ws;
    float* eff_c = ws;                 // 131072
    float* eoc   = ws + 131072;        // 131072
    float* nrm   = ws + 262144;        // 131072

    hipLaunchKernelGGL(K1_front, dim3(BB * MM), dim3(512), 0, stream,
                       pointers, contents, receivers, memories, W1, b1, W2, b2,
                       eff_c, outp_g, outc_g);
    hipLaunchKernelGGL(K2_route, dim3(BB * MM), dim3(256), 0, stream,
                       outp_g, outc_g, eff_c, eoc, nrm);
    hipLaunchKernelGGL(K3_stream, dim3(MM * 16 * BB), dim3(256), 0, stream,
                       memories, eoc, nrm, mems_out);
}